// Round 4
// baseline (394.411 us; speedup 1.0000x reference)
//
#include <hip/hip_runtime.h>

constexpr int NN = 50000;   // nodes
constexpr int NE = 800000;  // edges
constexpr int NG = 64;      // graphs
constexpr int DI = 64;      // in dim
constexpr int DH = 128;     // hidden dim
constexpr int DO = 3;       // out dim

constexpr int SCAN_B = 256;
constexpr int NB_SCAN = (NN + SCAN_B - 1) / SCAN_B;  // 196

// ---------------- CSR build ----------------
__global__ void k_zero_cnt(int* cnt) {
    int i = blockIdx.x * blockDim.x + threadIdx.x;
    if (i < NN) cnt[i] = 0;
}

__global__ void k_hist(const int* __restrict__ dst, int* __restrict__ cnt) {
    int e = blockIdx.x * blockDim.x + threadIdx.x;
    if (e < NE) atomicAdd(&cnt[dst[e]], 1);
}

__global__ void k_scan1(const int* __restrict__ cnt, int* __restrict__ rowptr,
                        int* __restrict__ partial) {
    __shared__ int sm[SCAN_B];
    int i = blockIdx.x * SCAN_B + threadIdx.x;
    int v = (i < NN) ? cnt[i] : 0;
    sm[threadIdx.x] = v;
    __syncthreads();
    for (int off = 1; off < SCAN_B; off <<= 1) {
        int add = (threadIdx.x >= off) ? sm[threadIdx.x - off] : 0;
        __syncthreads();
        sm[threadIdx.x] += add;
        __syncthreads();
    }
    if (i < NN) rowptr[i] = sm[threadIdx.x] - v;  // block-local exclusive
    if (threadIdx.x == SCAN_B - 1) partial[blockIdx.x] = sm[SCAN_B - 1];
}

__global__ void k_scan2(int* partial) {  // single block, NB_SCAN <= 256
    __shared__ int sm[SCAN_B];
    int v = (threadIdx.x < NB_SCAN) ? partial[threadIdx.x] : 0;
    sm[threadIdx.x] = v;
    __syncthreads();
    for (int off = 1; off < SCAN_B; off <<= 1) {
        int add = (threadIdx.x >= off) ? sm[threadIdx.x - off] : 0;
        __syncthreads();
        sm[threadIdx.x] += add;
        __syncthreads();
    }
    if (threadIdx.x < NB_SCAN) partial[threadIdx.x] = sm[threadIdx.x] - v;  // exclusive
}

__global__ void k_dinv(const int* __restrict__ cnt, float* __restrict__ dinv) {
    int i = blockIdx.x * blockDim.x + threadIdx.x;
    if (i < NN) dinv[i] = rsqrtf((float)(cnt[i] + 1));  // +1 self-loop, always >=1
}

// finalizes rowptr AND initializes cursor (aliased onto cnt — cnt is dead after k_dinv)
__global__ void k_scan3(int* __restrict__ rowptr, const int* __restrict__ partial,
                        int* __restrict__ cursor) {
    int i = blockIdx.x * blockDim.x + threadIdx.x;
    if (i < NN) {
        int r = rowptr[i] + partial[i >> 8];
        rowptr[i] = r;
        cursor[i] = r;
    }
    if (i == NN) rowptr[NN] = NE;
}

// fill packed (src, w) per edge; w = dinv[s]*dinv[d] reused by both layers
__global__ void k_fill(const int* __restrict__ src, const int* __restrict__ dst,
                       int* __restrict__ cursor, const float* __restrict__ dinv,
                       int2* __restrict__ csr) {
    int e = blockIdx.x * blockDim.x + threadIdx.x;
    if (e < NE) {
        int s = src[e], d = dst[e];
        int slot = atomicAdd(&cursor[d], 1);
        float w = dinv[s] * dinv[d];
        csr[slot] = make_int2(s, __float_as_int(w));
    }
}

// ---------------- gather aggregation ----------------
// out[n] = dinv[n]^2*h[n] + sum_in w_e * h[src_e]   (+bias, relu)
// One node per SUB-lane subgroup, float4 gathers, unroll-2 for MLP.
template <int D, bool BIAS_RELU>
__global__ __launch_bounds__(256) void k_agg2(const float* __restrict__ h,
                                              const int2* __restrict__ csr,
                                              const int* __restrict__ rowptr,
                                              const float* __restrict__ dinv,
                                              const float* __restrict__ bias,
                                              float* __restrict__ out) {
    constexpr int SUB = D / 4;        // lanes per node (16 for D=64, 32 for D=128)
    constexpr int NPB = 256 / SUB;    // nodes per block
    const int sub = threadIdx.x / SUB;
    const int sl = threadIdx.x % SUB;
    const int node = blockIdx.x * NPB + sub;
    if (node >= NN) return;

    const float dn = dinv[node];
    float4 acc;
    {
        float4 hv = *reinterpret_cast<const float4*>(h + (size_t)node * D + sl * 4);
        float w = dn * dn;
        acc.x = w * hv.x; acc.y = w * hv.y; acc.z = w * hv.z; acc.w = w * hv.w;
    }
    int j = rowptr[node];
    const int end = rowptr[node + 1];
    for (; j + 2 <= end; j += 2) {
        int2 e0 = csr[j];
        int2 e1 = csr[j + 1];
        float w0 = __int_as_float(e0.y);
        float w1 = __int_as_float(e1.y);
        float4 g0 = *reinterpret_cast<const float4*>(h + (size_t)e0.x * D + sl * 4);
        float4 g1 = *reinterpret_cast<const float4*>(h + (size_t)e1.x * D + sl * 4);
        acc.x = fmaf(w0, g0.x, acc.x); acc.y = fmaf(w0, g0.y, acc.y);
        acc.z = fmaf(w0, g0.z, acc.z); acc.w = fmaf(w0, g0.w, acc.w);
        acc.x = fmaf(w1, g1.x, acc.x); acc.y = fmaf(w1, g1.y, acc.y);
        acc.z = fmaf(w1, g1.z, acc.z); acc.w = fmaf(w1, g1.w, acc.w);
    }
    if (j < end) {
        int2 e0 = csr[j];
        float w0 = __int_as_float(e0.y);
        float4 g0 = *reinterpret_cast<const float4*>(h + (size_t)e0.x * D + sl * 4);
        acc.x = fmaf(w0, g0.x, acc.x); acc.y = fmaf(w0, g0.y, acc.y);
        acc.z = fmaf(w0, g0.z, acc.z); acc.w = fmaf(w0, g0.w, acc.w);
    }
    if (BIAS_RELU) {
        float4 bb = *reinterpret_cast<const float4*>(bias + sl * 4);
        acc.x = fmaxf(acc.x + bb.x, 0.0f);
        acc.y = fmaxf(acc.y + bb.y, 0.0f);
        acc.z = fmaxf(acc.z + bb.z, 0.0f);
        acc.w = fmaxf(acc.w + bb.w, 0.0f);
    }
    *reinterpret_cast<float4*>(out + (size_t)node * D + sl * 4) = acc;
}

// ---------------- GEMM: C[NN,DH] = A[NN,DIN] @ W[DIN,DH] (+bias, relu) ----------------
template <int DIN, bool BIAS_RELU>
__global__ __launch_bounds__(256) void k_gemm(const float* __restrict__ A,
                                              const float* __restrict__ W,
                                              const float* __restrict__ bias,
                                              float* __restrict__ C) {
    __shared__ float sW[DIN * DH];
    __shared__ float sA[16 * DIN];
    const int t = threadIdx.x;
    for (int i = t; i < DIN * DH; i += 256) sW[i] = W[i];
    const int row0 = blockIdx.x * 16;
    for (int i = t; i < 16 * DIN; i += 256) {
        int r = i / DIN, k = i - r * DIN;
        int gr = row0 + r;
        sA[i] = (gr < NN) ? A[(size_t)gr * DIN + k] : 0.0f;
    }
    __syncthreads();
    const int col = t & 127;
    const int rb = t >> 7;  // 0 or 1
    float acc[8] = {0.f, 0.f, 0.f, 0.f, 0.f, 0.f, 0.f, 0.f};
    for (int k = 0; k < DIN; k += 4) {
        float w0 = sW[(k + 0) * DH + col];
        float w1 = sW[(k + 1) * DH + col];
        float w2 = sW[(k + 2) * DH + col];
        float w3 = sW[(k + 3) * DH + col];
#pragma unroll
        for (int j = 0; j < 8; ++j) {
            float4 a = *reinterpret_cast<const float4*>(&sA[(rb + 2 * j) * DIN + k]);
            acc[j] = fmaf(a.x, w0, fmaf(a.y, w1, fmaf(a.z, w2, fmaf(a.w, w3, acc[j]))));
        }
    }
    float b = BIAS_RELU ? bias[col] : 0.0f;
#pragma unroll
    for (int j = 0; j < 8; ++j) {
        int gr = row0 + rb + 2 * j;
        if (gr < NN) {
            float r = acc[j];
            if (BIAS_RELU) r = fmaxf(r + b, 0.0f);
            C[(size_t)gr * DH + col] = r;
        }
    }
}

// ---------------- pooling ----------------
__global__ void k_gstart_zero(const int* __restrict__ batch, int* __restrict__ gstart,
                              float* __restrict__ pooled) {
    int i = blockIdx.x * blockDim.x + threadIdx.x;
    if (i < NG * DH) pooled[i] = 0.0f;
    if (blockIdx.x == 0 && threadIdx.x <= NG) {
        int g = threadIdx.x;
        int lo = 0, hi = NN;
        while (lo < hi) {
            int mid = (lo + hi) >> 1;
            if (batch[mid] < g) lo = mid + 1; else hi = mid;
        }
        gstart[g] = lo;
    }
}

constexpr int POOL_CHUNK = 64;
__global__ __launch_bounds__(256) void k_pool2(const float* __restrict__ h,
                                               const int* __restrict__ batch,
                                               float* __restrict__ pooled) {
    const int c = threadIdx.x & 127;    // channel
    const int half = threadIdx.x >> 7;  // 0/1: interleaved nodes
    const int n0 = blockIdx.x * POOL_CHUNK;
    const int nEnd = min(n0 + POOL_CHUNK, NN);
    float acc = 0.0f;
    int gcur = -1;
    for (int n = n0 + half; n < nEnd; n += 2) {
        int g = batch[n];
        if (g != gcur) {
            if (gcur >= 0) atomicAdd(&pooled[gcur * DH + c], acc);
            acc = 0.0f;
            gcur = g;
        }
        acc += h[(size_t)n * DH + c];
    }
    if (gcur >= 0) atomicAdd(&pooled[gcur * DH + c], acc);
}

__global__ void k_head(const float* __restrict__ pooled, const int* __restrict__ gstart,
                       const float* __restrict__ Wf, const float* __restrict__ bf,
                       float* __restrict__ out) {
    int t = threadIdx.x;
    if (t >= NG * DO) return;
    int g = t / DO, o = t - g * DO;
    float acc = 0.0f;
    for (int k = 0; k < DH; ++k) acc += pooled[g * DH + k] * Wf[k * DO + o];
    float cnt = fmaxf((float)(gstart[g + 1] - gstart[g]), 1.0f);
    out[t] = acc / cnt + bf[o];
}

extern "C" void kernel_launch(void* const* d_in, const int* in_sizes, int n_in,
                              void* d_out, int out_size, void* d_ws, size_t ws_size,
                              hipStream_t stream) {
    const float* x   = (const float*)d_in[0];
    const int* ei    = (const int*)d_in[1];  // [2, NE] row-major
    const int* batch = (const int*)d_in[2];
    const float* W1  = (const float*)d_in[3];
    const float* b1  = (const float*)d_in[4];
    const float* W2  = (const float*)d_in[5];
    const float* b2  = (const float*)d_in[6];
    const float* Wf  = (const float*)d_in[7];
    const float* bf  = (const float*)d_in[8];
    float* out = (float*)d_out;

    const int* src = ei;
    const int* dst = ei + NE;

    // workspace layout (~58.3 MB)
    int* cnt      = (int*)d_ws;              // 50048 (reused as cursor after k_dinv)
    int* rowptr   = cnt + 50048;             // 50056 (NN+1 used)
    int* partial  = rowptr + 50056;          // 256
    int* gstart   = partial + 256;           // 72
    int2* csr     = (int2*)(gstart + 72);    // 800000 int2 (8B-aligned: 100432*4 % 8 == 0)
    float* dinv   = (float*)(csr + 800000);  // 50048
    float* buf1   = dinv + 50048;            // 6,400,000
    float* buf2   = buf1 + 6400000;          // 6,400,000
    float* pooled = buf2 + 6400000;          // 8192

    const int B = 256;
    // CSR build + norms (order matters: dinv from cnt BEFORE scan3 clobbers cnt as cursor)
    k_zero_cnt<<<(NN + B - 1) / B, B, 0, stream>>>(cnt);
    k_hist<<<(NE + B - 1) / B, B, 0, stream>>>(dst, cnt);
    k_scan1<<<NB_SCAN, SCAN_B, 0, stream>>>(cnt, rowptr, partial);
    k_scan2<<<1, SCAN_B, 0, stream>>>(partial);
    k_dinv<<<(NN + B - 1) / B, B, 0, stream>>>(cnt, dinv);
    k_scan3<<<(NN + B) / B, B, 0, stream>>>(rowptr, partial, cnt /*cursor*/);
    k_fill<<<(NE + B - 1) / B, B, 0, stream>>>(src, dst, cnt /*cursor*/, dinv, csr);

    const int gemmGrid = (NN + 15) / 16;

    // layer 1: agg first (D=64, linearity), then GEMM + bias + relu
    k_agg2<DI, false><<<NN / 16, 256, 0, stream>>>(x, csr, rowptr, dinv, nullptr, buf1);
    k_gemm<DI, true><<<gemmGrid, 256, 0, stream>>>(buf1, W1, b1, buf2);  // h1

    // layer 2: GEMM first, then agg + bias + relu
    k_gemm<DH, false><<<gemmGrid, 256, 0, stream>>>(buf2, W2, nullptr, buf1);  // t = h1@W2
    k_agg2<DH, true><<<NN / 8, 256, 0, stream>>>(buf1, csr, rowptr, dinv, b2, buf2);  // h2

    // pool + head
    k_gstart_zero<<<32, 256, 0, stream>>>(batch, gstart, pooled);
    k_pool2<<<(NN + POOL_CHUNK - 1) / POOL_CHUNK, 256, 0, stream>>>(buf2, batch, pooled);
    k_head<<<1, 256, 0, stream>>>(pooled, gstart, Wf, bf, out);
}

// Round 5
// 322.599 us; speedup vs baseline: 1.2226x; 1.2226x over previous
//
#include <hip/hip_runtime.h>

constexpr int NN = 50000;   // nodes
constexpr int NE = 800000;  // edges
constexpr int NG = 64;      // graphs
constexpr int DI = 64;      // in dim
constexpr int DH = 128;     // hidden dim
constexpr int DO = 3;       // out dim

constexpr int SCAN_B = 256;
constexpr int NB_SCAN = (NN + SCAN_B - 1) / SCAN_B;  // 196

// ---------------- CSR build ----------------
__global__ void k_zero_cnt(int* cnt) {
    int i = blockIdx.x * blockDim.x + threadIdx.x;
    if (i < NN) cnt[i] = 0;
}

__global__ void k_hist(const int* __restrict__ dst, int* __restrict__ cnt) {
    int e = blockIdx.x * blockDim.x + threadIdx.x;
    if (e < NE) atomicAdd(&cnt[dst[e]], 1);
}

__global__ void k_scan1(const int* __restrict__ cnt, int* __restrict__ rowptr,
                        int* __restrict__ partial) {
    __shared__ int sm[SCAN_B];
    int i = blockIdx.x * SCAN_B + threadIdx.x;
    int v = (i < NN) ? cnt[i] : 0;
    sm[threadIdx.x] = v;
    __syncthreads();
    for (int off = 1; off < SCAN_B; off <<= 1) {
        int add = (threadIdx.x >= off) ? sm[threadIdx.x - off] : 0;
        __syncthreads();
        sm[threadIdx.x] += add;
        __syncthreads();
    }
    if (i < NN) rowptr[i] = sm[threadIdx.x] - v;  // block-local exclusive
    if (threadIdx.x == SCAN_B - 1) partial[blockIdx.x] = sm[SCAN_B - 1];
}

__global__ void k_scan2(int* partial) {  // single block, NB_SCAN <= 256
    __shared__ int sm[SCAN_B];
    int v = (threadIdx.x < NB_SCAN) ? partial[threadIdx.x] : 0;
    sm[threadIdx.x] = v;
    __syncthreads();
    for (int off = 1; off < SCAN_B; off <<= 1) {
        int add = (threadIdx.x >= off) ? sm[threadIdx.x - off] : 0;
        __syncthreads();
        sm[threadIdx.x] += add;
        __syncthreads();
    }
    if (threadIdx.x < NB_SCAN) partial[threadIdx.x] = sm[threadIdx.x] - v;  // exclusive
}

__global__ void k_dinv(const int* __restrict__ cnt, float* __restrict__ dinv) {
    int i = blockIdx.x * blockDim.x + threadIdx.x;
    if (i < NN) dinv[i] = rsqrtf((float)(cnt[i] + 1));  // +1 self-loop, always >=1
}

// finalizes rowptr AND initializes cursor (aliased onto cnt — cnt is dead after k_dinv)
__global__ void k_scan3(int* __restrict__ rowptr, const int* __restrict__ partial,
                        int* __restrict__ cursor) {
    int i = blockIdx.x * blockDim.x + threadIdx.x;
    if (i < NN) {
        int r = rowptr[i] + partial[i >> 8];
        rowptr[i] = r;
        cursor[i] = r;
    }
    if (i == NN) rowptr[NN] = NE;
}

// fill packed (src, w) per edge; w = dinv[s]*dinv[d] reused by both layers
__global__ void k_fill(const int* __restrict__ src, const int* __restrict__ dst,
                       int* __restrict__ cursor, const float* __restrict__ dinv,
                       int2* __restrict__ csr) {
    int e = blockIdx.x * blockDim.x + threadIdx.x;
    if (e < NE) {
        int s = src[e], d = dst[e];
        int slot = atomicAdd(&cursor[d], 1);
        float w = dinv[s] * dinv[d];
        csr[slot] = make_int2(s, __float_as_int(w));
    }
}

// ---------------- gather aggregation ----------------
// out[n] = dinv[n]^2*h[n] + sum_in w_e * h[src_e]   (+bias, relu)
template <int D, bool BIAS_RELU>
__global__ __launch_bounds__(256) void k_agg2(const float* __restrict__ h,
                                              const int2* __restrict__ csr,
                                              const int* __restrict__ rowptr,
                                              const float* __restrict__ dinv,
                                              const float* __restrict__ bias,
                                              float* __restrict__ out) {
    constexpr int SUB = D / 4;        // lanes per node (16 for D=64, 32 for D=128)
    constexpr int NPB = 256 / SUB;    // nodes per block
    const int sub = threadIdx.x / SUB;
    const int sl = threadIdx.x % SUB;
    const int node = blockIdx.x * NPB + sub;
    if (node >= NN) return;

    const float dn = dinv[node];
    float4 acc;
    {
        float4 hv = *reinterpret_cast<const float4*>(h + (size_t)node * D + sl * 4);
        float w = dn * dn;
        acc.x = w * hv.x; acc.y = w * hv.y; acc.z = w * hv.z; acc.w = w * hv.w;
    }
    int j = rowptr[node];
    const int end = rowptr[node + 1];
    for (; j + 2 <= end; j += 2) {
        int2 e0 = csr[j];
        int2 e1 = csr[j + 1];
        float w0 = __int_as_float(e0.y);
        float w1 = __int_as_float(e1.y);
        float4 g0 = *reinterpret_cast<const float4*>(h + (size_t)e0.x * D + sl * 4);
        float4 g1 = *reinterpret_cast<const float4*>(h + (size_t)e1.x * D + sl * 4);
        acc.x = fmaf(w0, g0.x, acc.x); acc.y = fmaf(w0, g0.y, acc.y);
        acc.z = fmaf(w0, g0.z, acc.z); acc.w = fmaf(w0, g0.w, acc.w);
        acc.x = fmaf(w1, g1.x, acc.x); acc.y = fmaf(w1, g1.y, acc.y);
        acc.z = fmaf(w1, g1.z, acc.z); acc.w = fmaf(w1, g1.w, acc.w);
    }
    if (j < end) {
        int2 e0 = csr[j];
        float w0 = __int_as_float(e0.y);
        float4 g0 = *reinterpret_cast<const float4*>(h + (size_t)e0.x * D + sl * 4);
        acc.x = fmaf(w0, g0.x, acc.x); acc.y = fmaf(w0, g0.y, acc.y);
        acc.z = fmaf(w0, g0.z, acc.z); acc.w = fmaf(w0, g0.w, acc.w);
    }
    if (BIAS_RELU) {
        float4 bb = *reinterpret_cast<const float4*>(bias + sl * 4);
        acc.x = fmaxf(acc.x + bb.x, 0.0f);
        acc.y = fmaxf(acc.y + bb.y, 0.0f);
        acc.z = fmaxf(acc.z + bb.z, 0.0f);
        acc.w = fmaxf(acc.w + bb.w, 0.0f);
    }
    *reinterpret_cast<float4*>(out + (size_t)node * D + sl * 4) = acc;
}

// ---------------- GEMM: C[NN,DH] = A[NN,DIN] @ W[DIN,DH] (+bias, relu) ----------------
// W staged TRANSPOSED in LDS (sWt[col][k], k-stride padded) so each thread reads
// its 4 k-values as one ds_read_b128. A rows broadcast (uniform addr per wave).
// #pragma unroll 2 pins register pressure (round-4 lesson: full unroll -> 256 VGPR + spills).
template <int DIN, bool BIAS_RELU>
__global__ __launch_bounds__(256) void k_gemm(const float* __restrict__ A,
                                              const float* __restrict__ W,
                                              const float* __restrict__ bias,
                                              float* __restrict__ C) {
    constexpr int KP = DIN + 4;         // padded k-stride: spreads b128 across banks
    __shared__ float sWt[DH * KP];
    __shared__ float sA[16 * DIN];
    const int t = threadIdx.x;
    for (int i = t; i < DIN * DH; i += 256) {
        int k = i >> 7, c = i & 127;    // W is [DIN][DH] row-major
        sWt[c * KP + k] = W[i];
    }
    const int row0 = blockIdx.x * 16;
    for (int i = t; i < 16 * DIN; i += 256) {
        int r = i / DIN, k = i - r * DIN;
        int gr = row0 + r;
        sA[i] = (gr < NN) ? A[(size_t)gr * DIN + k] : 0.0f;
    }
    __syncthreads();
    const int col = t & 127;
    const int rb = t >> 7;  // 0 or 1
    float acc[8] = {0.f, 0.f, 0.f, 0.f, 0.f, 0.f, 0.f, 0.f};
#pragma unroll 2
    for (int k = 0; k < DIN; k += 4) {
        float4 w = *reinterpret_cast<const float4*>(&sWt[col * KP + k]);
#pragma unroll
        for (int j = 0; j < 8; ++j) {
            float4 a = *reinterpret_cast<const float4*>(&sA[(rb + 2 * j) * DIN + k]);
            acc[j] = fmaf(a.x, w.x, fmaf(a.y, w.y, fmaf(a.z, w.z, fmaf(a.w, w.w, acc[j]))));
        }
    }
    float b = BIAS_RELU ? bias[col] : 0.0f;
#pragma unroll
    for (int j = 0; j < 8; ++j) {
        int gr = row0 + rb + 2 * j;
        if (gr < NN) {
            float r = acc[j];
            if (BIAS_RELU) r = fmaxf(r + b, 0.0f);
            C[(size_t)gr * DH + col] = r;
        }
    }
}

// ---------------- pooling ----------------
__global__ void k_gstart_zero(const int* __restrict__ batch, int* __restrict__ gstart,
                              float* __restrict__ pooled) {
    int i = blockIdx.x * blockDim.x + threadIdx.x;
    if (i < NG * DH) pooled[i] = 0.0f;
    if (blockIdx.x == 0 && threadIdx.x <= NG) {
        int g = threadIdx.x;
        int lo = 0, hi = NN;
        while (lo < hi) {
            int mid = (lo + hi) >> 1;
            if (batch[mid] < g) lo = mid + 1; else hi = mid;
        }
        gstart[g] = lo;
    }
}

constexpr int POOL_CHUNK = 64;
__global__ __launch_bounds__(256) void k_pool2(const float* __restrict__ h,
                                               const int* __restrict__ batch,
                                               float* __restrict__ pooled) {
    const int c = threadIdx.x & 127;    // channel
    const int half = threadIdx.x >> 7;  // 0/1: interleaved nodes
    const int n0 = blockIdx.x * POOL_CHUNK;
    const int nEnd = min(n0 + POOL_CHUNK, NN);
    float acc = 0.0f;
    int gcur = -1;
    for (int n = n0 + half; n < nEnd; n += 2) {
        int g = batch[n];
        if (g != gcur) {
            if (gcur >= 0) atomicAdd(&pooled[gcur * DH + c], acc);
            acc = 0.0f;
            gcur = g;
        }
        acc += h[(size_t)n * DH + c];
    }
    if (gcur >= 0) atomicAdd(&pooled[gcur * DH + c], acc);
}

__global__ void k_head(const float* __restrict__ pooled, const int* __restrict__ gstart,
                       const float* __restrict__ Wf, const float* __restrict__ bf,
                       float* __restrict__ out) {
    int t = threadIdx.x;
    if (t >= NG * DO) return;
    int g = t / DO, o = t - g * DO;
    float acc = 0.0f;
    for (int k = 0; k < DH; ++k) acc += pooled[g * DH + k] * Wf[k * DO + o];
    float cnt = fmaxf((float)(gstart[g + 1] - gstart[g]), 1.0f);
    out[t] = acc / cnt + bf[o];
}

extern "C" void kernel_launch(void* const* d_in, const int* in_sizes, int n_in,
                              void* d_out, int out_size, void* d_ws, size_t ws_size,
                              hipStream_t stream) {
    const float* x   = (const float*)d_in[0];
    const int* ei    = (const int*)d_in[1];  // [2, NE] row-major
    const int* batch = (const int*)d_in[2];
    const float* W1  = (const float*)d_in[3];
    const float* b1  = (const float*)d_in[4];
    const float* W2  = (const float*)d_in[5];
    const float* b2  = (const float*)d_in[6];
    const float* Wf  = (const float*)d_in[7];
    const float* bf  = (const float*)d_in[8];
    float* out = (float*)d_out;

    const int* src = ei;
    const int* dst = ei + NE;

    // workspace layout (~58.3 MB)
    int* cnt      = (int*)d_ws;              // 50048 (reused as cursor after k_dinv)
    int* rowptr   = cnt + 50048;             // 50056 (NN+1 used)
    int* partial  = rowptr + 50056;          // 256
    int* gstart   = partial + 256;           // 72
    int2* csr     = (int2*)(gstart + 72);    // 800000 int2
    float* dinv   = (float*)(csr + 800000);  // 50048
    float* buf1   = dinv + 50048;            // 6,400,000
    float* buf2   = buf1 + 6400000;          // 6,400,000
    float* pooled = buf2 + 6400000;          // 8192

    const int B = 256;
    // CSR build + norms (order matters: dinv from cnt BEFORE scan3 clobbers cnt as cursor)
    k_zero_cnt<<<(NN + B - 1) / B, B, 0, stream>>>(cnt);
    k_hist<<<(NE + B - 1) / B, B, 0, stream>>>(dst, cnt);
    k_scan1<<<NB_SCAN, SCAN_B, 0, stream>>>(cnt, rowptr, partial);
    k_scan2<<<1, SCAN_B, 0, stream>>>(partial);
    k_dinv<<<(NN + B - 1) / B, B, 0, stream>>>(cnt, dinv);
    k_scan3<<<(NN + B) / B, B, 0, stream>>>(rowptr, partial, cnt /*cursor*/);
    k_fill<<<(NE + B - 1) / B, B, 0, stream>>>(src, dst, cnt /*cursor*/, dinv, csr);

    const int gemmGrid = (NN + 15) / 16;

    // layer 1: agg first (D=64, linearity), then GEMM + bias + relu
    k_agg2<DI, false><<<NN / 16, 256, 0, stream>>>(x, csr, rowptr, dinv, nullptr, buf1);
    k_gemm<DI, true><<<gemmGrid, 256, 0, stream>>>(buf1, W1, b1, buf2);  // h1

    // layer 2: GEMM first, then agg + bias + relu
    k_gemm<DH, false><<<gemmGrid, 256, 0, stream>>>(buf2, W2, nullptr, buf1);  // t = h1@W2
    k_agg2<DH, true><<<NN / 8, 256, 0, stream>>>(buf1, csr, rowptr, dinv, b2, buf2);  // h2

    // pool + head
    k_gstart_zero<<<32, 256, 0, stream>>>(batch, gstart, pooled);
    k_pool2<<<(NN + POOL_CHUNK - 1) / POOL_CHUNK, 256, 0, stream>>>(buf2, batch, pooled);
    k_head<<<1, 256, 0, stream>>>(pooled, gstart, Wf, bf, out);
}

// Round 6
// 270.018 us; speedup vs baseline: 1.4607x; 1.1947x over previous
//
#include <hip/hip_runtime.h>

constexpr int NN = 50000;   // nodes
constexpr int NE = 800000;  // edges
constexpr int NG = 64;      // graphs
constexpr int DI = 64;      // in dim
constexpr int DH = 128;     // hidden dim
constexpr int DO = 3;       // out dim

constexpr int SCAN_B = 256;
constexpr int NB_SCAN = (NN + SCAN_B - 1) / SCAN_B;  // 196

// ---------------- CSR build ----------------
__global__ void k_zero_cnt(int* cnt) {
    int i = blockIdx.x * blockDim.x + threadIdx.x;
    if (i < NN) cnt[i] = 0;
}

__global__ void k_hist(const int* __restrict__ dst, int* __restrict__ cnt) {
    int e = blockIdx.x * blockDim.x + threadIdx.x;
    if (e < NE) atomicAdd(&cnt[dst[e]], 1);
}

__global__ void k_scan1(const int* __restrict__ cnt, int* __restrict__ rowptr,
                        int* __restrict__ partial) {
    __shared__ int sm[SCAN_B];
    int i = blockIdx.x * SCAN_B + threadIdx.x;
    int v = (i < NN) ? cnt[i] : 0;
    sm[threadIdx.x] = v;
    __syncthreads();
    for (int off = 1; off < SCAN_B; off <<= 1) {
        int add = (threadIdx.x >= off) ? sm[threadIdx.x - off] : 0;
        __syncthreads();
        sm[threadIdx.x] += add;
        __syncthreads();
    }
    if (i < NN) rowptr[i] = sm[threadIdx.x] - v;  // block-local exclusive
    if (threadIdx.x == SCAN_B - 1) partial[blockIdx.x] = sm[SCAN_B - 1];
}

__global__ void k_scan2(int* partial) {  // single block, NB_SCAN <= 256
    __shared__ int sm[SCAN_B];
    int v = (threadIdx.x < NB_SCAN) ? partial[threadIdx.x] : 0;
    sm[threadIdx.x] = v;
    __syncthreads();
    for (int off = 1; off < SCAN_B; off <<= 1) {
        int add = (threadIdx.x >= off) ? sm[threadIdx.x - off] : 0;
        __syncthreads();
        sm[threadIdx.x] += add;
        __syncthreads();
    }
    if (threadIdx.x < NB_SCAN) partial[threadIdx.x] = sm[threadIdx.x] - v;  // exclusive
}

__global__ void k_dinv(const int* __restrict__ cnt, float* __restrict__ dinv) {
    int i = blockIdx.x * blockDim.x + threadIdx.x;
    if (i < NN) dinv[i] = rsqrtf((float)(cnt[i] + 1));  // +1 self-loop, always >=1
}

// finalizes rowptr AND initializes cursor (aliased onto cnt — cnt is dead after k_dinv)
__global__ void k_scan3(int* __restrict__ rowptr, const int* __restrict__ partial,
                        int* __restrict__ cursor) {
    int i = blockIdx.x * blockDim.x + threadIdx.x;
    if (i < NN) {
        int r = rowptr[i] + partial[i >> 8];
        rowptr[i] = r;
        cursor[i] = r;
    }
    if (i == NN) rowptr[NN] = NE;
}

// fill packed (src, w) per edge; w = dinv[s]*dinv[d] reused by both layers
__global__ void k_fill(const int* __restrict__ src, const int* __restrict__ dst,
                       int* __restrict__ cursor, const float* __restrict__ dinv,
                       int2* __restrict__ csr) {
    int e = blockIdx.x * blockDim.x + threadIdx.x;
    if (e < NE) {
        int s = src[e], d = dst[e];
        int slot = atomicAdd(&cursor[d], 1);
        float w = dinv[s] * dinv[d];
        csr[slot] = make_int2(s, __float_as_int(w));
    }
}

// ---------------- gather aggregation ----------------
// out[n] = dinv[n]^2*h[n] + sum_in w_e * h[src_e]   (+bias, relu)
template <int D, bool BIAS_RELU>
__global__ __launch_bounds__(256) void k_agg2(const float* __restrict__ h,
                                              const int2* __restrict__ csr,
                                              const int* __restrict__ rowptr,
                                              const float* __restrict__ dinv,
                                              const float* __restrict__ bias,
                                              float* __restrict__ out) {
    constexpr int SUB = D / 4;        // lanes per node (16 for D=64, 32 for D=128)
    constexpr int NPB = 256 / SUB;    // nodes per block
    const int sub = threadIdx.x / SUB;
    const int sl = threadIdx.x % SUB;
    const int node = blockIdx.x * NPB + sub;
    if (node >= NN) return;

    const float dn = dinv[node];
    float4 acc;
    {
        float4 hv = *reinterpret_cast<const float4*>(h + (size_t)node * D + sl * 4);
        float w = dn * dn;
        acc.x = w * hv.x; acc.y = w * hv.y; acc.z = w * hv.z; acc.w = w * hv.w;
    }
    int j = rowptr[node];
    const int end = rowptr[node + 1];
    for (; j + 2 <= end; j += 2) {
        int2 e0 = csr[j];
        int2 e1 = csr[j + 1];
        float w0 = __int_as_float(e0.y);
        float w1 = __int_as_float(e1.y);
        float4 g0 = *reinterpret_cast<const float4*>(h + (size_t)e0.x * D + sl * 4);
        float4 g1 = *reinterpret_cast<const float4*>(h + (size_t)e1.x * D + sl * 4);
        acc.x = fmaf(w0, g0.x, acc.x); acc.y = fmaf(w0, g0.y, acc.y);
        acc.z = fmaf(w0, g0.z, acc.z); acc.w = fmaf(w0, g0.w, acc.w);
        acc.x = fmaf(w1, g1.x, acc.x); acc.y = fmaf(w1, g1.y, acc.y);
        acc.z = fmaf(w1, g1.z, acc.z); acc.w = fmaf(w1, g1.w, acc.w);
    }
    if (j < end) {
        int2 e0 = csr[j];
        float w0 = __int_as_float(e0.y);
        float4 g0 = *reinterpret_cast<const float4*>(h + (size_t)e0.x * D + sl * 4);
        acc.x = fmaf(w0, g0.x, acc.x); acc.y = fmaf(w0, g0.y, acc.y);
        acc.z = fmaf(w0, g0.z, acc.z); acc.w = fmaf(w0, g0.w, acc.w);
    }
    if (BIAS_RELU) {
        float4 bb = *reinterpret_cast<const float4*>(bias + sl * 4);
        acc.x = fmaxf(acc.x + bb.x, 0.0f);
        acc.y = fmaxf(acc.y + bb.y, 0.0f);
        acc.z = fmaxf(acc.z + bb.z, 0.0f);
        acc.w = fmaxf(acc.w + bb.w, 0.0f);
    }
    *reinterpret_cast<float4*>(out + (size_t)node * D + sl * 4) = acc;
}

// ---------------- GEMM v3: C[NN,DH] = A[NN,DIN] @ W[DIN,DH] (+bias, relu) ----------------
// Tile M=64 x N=128, K-chunks of 32. Per thread: 8 rows x 4 cols = 32 acc.
// sW kept row-major [k][c] (reads hit the 512B/instr bandwidth floor, no transpose);
// sA row-major [r][k] padded to 36 (staging stores <=2-way). 25.6 KB LDS total.
// Inner 4k-step: 8 broadcast b128 (A) + 4 b128 (W) + 128 FMA -> 10.7 FMA/LDS-instr.
__device__ inline float4 fmaf4(float s, float4 w, float4 a) {
    a.x = fmaf(s, w.x, a.x); a.y = fmaf(s, w.y, a.y);
    a.z = fmaf(s, w.z, a.z); a.w = fmaf(s, w.w, a.w);
    return a;
}

template <int DIN, bool BIAS_RELU>
__global__ __launch_bounds__(256) void k_gemm3(const float* __restrict__ A,
                                               const float* __restrict__ W,
                                               const float* __restrict__ bias,
                                               float* __restrict__ C) {
    constexpr int KT = 32;
    constexpr int NT = DIN / KT;  // k-tiles (2 or 4)
    constexpr int AP = KT + 4;    // padded sA row stride (36)
    __shared__ float sW[KT * DH];   // [k][c] row-major, 16 KB
    __shared__ float sA[64 * AP];   // [r][k] padded, 9.2 KB
    const int t = threadIdx.x;
    const int cg = t & 31;   // col group: cols cg*4..+3
    const int rg = t >> 5;   // row group: rows rg*8..+7
    const int row0 = blockIdx.x * 64;
    const int sr = t >> 2;   // staging row 0..63
    const int kq = t & 3;    // staging k-quad

    float4 acc[8];
#pragma unroll
    for (int j = 0; j < 8; ++j) acc[j] = make_float4(0.f, 0.f, 0.f, 0.f);

    for (int tile = 0; tile < NT; ++tile) {
        if (tile) __syncthreads();
        // stage W chunk (rows [tile*KT, +KT) of W[DIN][DH]) — straight float4 copy
        {
            const float4* Wg = reinterpret_cast<const float4*>(W + tile * KT * DH);
            float4* sW4 = reinterpret_cast<float4*>(sW);
#pragma unroll
            for (int i = 0; i < (KT * DH / 4) / 256; ++i)  // 4 iters
                sW4[t + 256 * i] = Wg[t + 256 * i];
        }
        // stage A chunk: 64 rows x 32 k, 2 float4 per thread
        {
            int gr = row0 + sr;
            float4 v0 = make_float4(0.f, 0.f, 0.f, 0.f), v1 = v0;
            if (gr < NN) {
                const float* Ag = A + (size_t)gr * DIN + tile * KT + kq * 8;
                v0 = *reinterpret_cast<const float4*>(Ag);
                v1 = *reinterpret_cast<const float4*>(Ag + 4);
            }
            *reinterpret_cast<float4*>(&sA[sr * AP + kq * 8]) = v0;
            *reinterpret_cast<float4*>(&sA[sr * AP + kq * 8 + 4]) = v1;
        }
        __syncthreads();
        // compute: 8 steps of 4k
#pragma unroll 2
        for (int kk = 0; kk < KT; kk += 4) {
            float4 w0 = *reinterpret_cast<const float4*>(&sW[(kk + 0) * DH + cg * 4]);
            float4 w1 = *reinterpret_cast<const float4*>(&sW[(kk + 1) * DH + cg * 4]);
            float4 w2 = *reinterpret_cast<const float4*>(&sW[(kk + 2) * DH + cg * 4]);
            float4 w3 = *reinterpret_cast<const float4*>(&sW[(kk + 3) * DH + cg * 4]);
#pragma unroll
            for (int j = 0; j < 8; ++j) {
                float4 a = *reinterpret_cast<const float4*>(&sA[(rg * 8 + j) * AP + kk]);
                acc[j] = fmaf4(a.x, w0, acc[j]);
                acc[j] = fmaf4(a.y, w1, acc[j]);
                acc[j] = fmaf4(a.z, w2, acc[j]);
                acc[j] = fmaf4(a.w, w3, acc[j]);
            }
        }
    }
    // epilogue
    float4 bb = make_float4(0.f, 0.f, 0.f, 0.f);
    if (BIAS_RELU) bb = *reinterpret_cast<const float4*>(bias + cg * 4);
#pragma unroll
    for (int j = 0; j < 8; ++j) {
        int gr = row0 + rg * 8 + j;
        if (gr < NN) {
            float4 r = acc[j];
            if (BIAS_RELU) {
                r.x = fmaxf(r.x + bb.x, 0.f); r.y = fmaxf(r.y + bb.y, 0.f);
                r.z = fmaxf(r.z + bb.z, 0.f); r.w = fmaxf(r.w + bb.w, 0.f);
            }
            *reinterpret_cast<float4*>(C + (size_t)gr * DH + cg * 4) = r;
        }
    }
}

// ---------------- pooling ----------------
__global__ void k_gstart_zero(const int* __restrict__ batch, int* __restrict__ gstart,
                              float* __restrict__ pooled) {
    int i = blockIdx.x * blockDim.x + threadIdx.x;
    if (i < NG * DH) pooled[i] = 0.0f;
    if (blockIdx.x == 0 && threadIdx.x <= NG) {
        int g = threadIdx.x;
        int lo = 0, hi = NN;
        while (lo < hi) {
            int mid = (lo + hi) >> 1;
            if (batch[mid] < g) lo = mid + 1; else hi = mid;
        }
        gstart[g] = lo;
    }
}

constexpr int POOL_CHUNK = 64;
__global__ __launch_bounds__(256) void k_pool2(const float* __restrict__ h,
                                               const int* __restrict__ batch,
                                               float* __restrict__ pooled) {
    const int c = threadIdx.x & 127;    // channel
    const int half = threadIdx.x >> 7;  // 0/1: interleaved nodes
    const int n0 = blockIdx.x * POOL_CHUNK;
    const int nEnd = min(n0 + POOL_CHUNK, NN);
    float acc = 0.0f;
    int gcur = -1;
    for (int n = n0 + half; n < nEnd; n += 2) {
        int g = batch[n];
        if (g != gcur) {
            if (gcur >= 0) atomicAdd(&pooled[gcur * DH + c], acc);
            acc = 0.0f;
            gcur = g;
        }
        acc += h[(size_t)n * DH + c];
    }
    if (gcur >= 0) atomicAdd(&pooled[gcur * DH + c], acc);
}

__global__ void k_head(const float* __restrict__ pooled, const int* __restrict__ gstart,
                       const float* __restrict__ Wf, const float* __restrict__ bf,
                       float* __restrict__ out) {
    int t = threadIdx.x;
    if (t >= NG * DO) return;
    int g = t / DO, o = t - g * DO;
    float acc = 0.0f;
    for (int k = 0; k < DH; ++k) acc += pooled[g * DH + k] * Wf[k * DO + o];
    float cnt = fmaxf((float)(gstart[g + 1] - gstart[g]), 1.0f);
    out[t] = acc / cnt + bf[o];
}

extern "C" void kernel_launch(void* const* d_in, const int* in_sizes, int n_in,
                              void* d_out, int out_size, void* d_ws, size_t ws_size,
                              hipStream_t stream) {
    const float* x   = (const float*)d_in[0];
    const int* ei    = (const int*)d_in[1];  // [2, NE] row-major
    const int* batch = (const int*)d_in[2];
    const float* W1  = (const float*)d_in[3];
    const float* b1  = (const float*)d_in[4];
    const float* W2  = (const float*)d_in[5];
    const float* b2  = (const float*)d_in[6];
    const float* Wf  = (const float*)d_in[7];
    const float* bf  = (const float*)d_in[8];
    float* out = (float*)d_out;

    const int* src = ei;
    const int* dst = ei + NE;

    // workspace layout (~58.3 MB)
    int* cnt      = (int*)d_ws;              // 50048 (reused as cursor after k_dinv)
    int* rowptr   = cnt + 50048;             // 50056 (NN+1 used)
    int* partial  = rowptr + 50056;          // 256
    int* gstart   = partial + 256;           // 72
    int2* csr     = (int2*)(gstart + 72);    // 800000 int2
    float* dinv   = (float*)(csr + 800000);  // 50048
    float* buf1   = dinv + 50048;            // 6,400,000
    float* buf2   = buf1 + 6400000;          // 6,400,000
    float* pooled = buf2 + 6400000;          // 8192

    const int B = 256;
    // CSR build + norms (order matters: dinv from cnt BEFORE scan3 clobbers cnt as cursor)
    k_zero_cnt<<<(NN + B - 1) / B, B, 0, stream>>>(cnt);
    k_hist<<<(NE + B - 1) / B, B, 0, stream>>>(dst, cnt);
    k_scan1<<<NB_SCAN, SCAN_B, 0, stream>>>(cnt, rowptr, partial);
    k_scan2<<<1, SCAN_B, 0, stream>>>(partial);
    k_dinv<<<(NN + B - 1) / B, B, 0, stream>>>(cnt, dinv);
    k_scan3<<<(NN + B) / B, B, 0, stream>>>(rowptr, partial, cnt /*cursor*/);
    k_fill<<<(NE + B - 1) / B, B, 0, stream>>>(src, dst, cnt /*cursor*/, dinv, csr);

    const int gemmGrid = (NN + 63) / 64;  // 782

    // layer 1: agg first (D=64, linearity), then GEMM + bias + relu
    k_agg2<DI, false><<<NN / 16, 256, 0, stream>>>(x, csr, rowptr, dinv, nullptr, buf1);
    k_gemm3<DI, true><<<gemmGrid, 256, 0, stream>>>(buf1, W1, b1, buf2);  // h1

    // layer 2: GEMM first, then agg + bias + relu
    k_gemm3<DH, false><<<gemmGrid, 256, 0, stream>>>(buf2, W2, nullptr, buf1);  // t = h1@W2
    k_agg2<DH, true><<<NN / 8, 256, 0, stream>>>(buf1, csr, rowptr, dinv, b2, buf2);  // h2

    // pool + head
    k_gstart_zero<<<32, 256, 0, stream>>>(batch, gstart, pooled);
    k_pool2<<<(NN + POOL_CHUNK - 1) / POOL_CHUNK, 256, 0, stream>>>(buf2, batch, pooled);
    k_head<<<1, 256, 0, stream>>>(pooled, gstart, Wf, bf, out);
}

// Round 7
// 264.793 us; speedup vs baseline: 1.4895x; 1.0197x over previous
//
#include <hip/hip_runtime.h>

constexpr int NN = 50000;   // nodes
constexpr int NE = 800000;  // edges
constexpr int NG = 64;      // graphs
constexpr int DI = 64;      // in dim
constexpr int DH = 128;     // hidden dim
constexpr int DO = 3;       // out dim

constexpr int SCAN_B = 256;
constexpr int NB_SCAN = (NN + SCAN_B - 1) / SCAN_B;  // 196

// ---------------- CSR build ----------------
__global__ void k_zero_cnt(int* cnt) {
    int i = blockIdx.x * blockDim.x + threadIdx.x;
    if (i < NN) cnt[i] = 0;
}

__global__ void k_hist(const int* __restrict__ dst, int* __restrict__ cnt) {
    int e = blockIdx.x * blockDim.x + threadIdx.x;
    if (e < NE) atomicAdd(&cnt[dst[e]], 1);
}

__global__ void k_scan1(const int* __restrict__ cnt, int* __restrict__ rowptr,
                        int* __restrict__ partial) {
    __shared__ int sm[SCAN_B];
    int i = blockIdx.x * SCAN_B + threadIdx.x;
    int v = (i < NN) ? cnt[i] : 0;
    sm[threadIdx.x] = v;
    __syncthreads();
    for (int off = 1; off < SCAN_B; off <<= 1) {
        int add = (threadIdx.x >= off) ? sm[threadIdx.x - off] : 0;
        __syncthreads();
        sm[threadIdx.x] += add;
        __syncthreads();
    }
    if (i < NN) rowptr[i] = sm[threadIdx.x] - v;  // block-local exclusive
    if (threadIdx.x == SCAN_B - 1) partial[blockIdx.x] = sm[SCAN_B - 1];
}

__global__ void k_scan2(int* partial) {  // single block, NB_SCAN <= 256
    __shared__ int sm[SCAN_B];
    int v = (threadIdx.x < NB_SCAN) ? partial[threadIdx.x] : 0;
    sm[threadIdx.x] = v;
    __syncthreads();
    for (int off = 1; off < SCAN_B; off <<= 1) {
        int add = (threadIdx.x >= off) ? sm[threadIdx.x - off] : 0;
        __syncthreads();
        sm[threadIdx.x] += add;
        __syncthreads();
    }
    if (threadIdx.x < NB_SCAN) partial[threadIdx.x] = sm[threadIdx.x] - v;  // exclusive
}

// finalizes rowptr, computes dinv from cnt, then re-inits cnt as the fill cursor
__global__ void k_scan3(int* __restrict__ rowptr, const int* __restrict__ partial,
                        int* __restrict__ cnt_cursor, float* __restrict__ dinv) {
    int i = blockIdx.x * blockDim.x + threadIdx.x;
    if (i < NN) {
        int r = rowptr[i] + partial[i >> 8];
        rowptr[i] = r;
        dinv[i] = rsqrtf((float)(cnt_cursor[i] + 1));  // read cnt BEFORE overwrite
        cnt_cursor[i] = r;
    }
    if (i == NN) rowptr[NN] = NE;
}

// fill packed (src, w) per edge; w = dinv[s]*dinv[d] reused by both layers
__global__ void k_fill(const int* __restrict__ src, const int* __restrict__ dst,
                       int* __restrict__ cursor, const float* __restrict__ dinv,
                       int2* __restrict__ csr) {
    int e = blockIdx.x * blockDim.x + threadIdx.x;
    if (e < NE) {
        int s = src[e], d = dst[e];
        int slot = atomicAdd(&cursor[d], 1);
        float w = dinv[s] * dinv[d];
        csr[slot] = make_int2(s, __float_as_int(w));
    }
}

// ---------------- gather aggregation v3 ----------------
// out[n] = dinv[n]^2*h[n] + sum_in w_e * h[src_e]   (+bias, relu)
// Paired-edge int4 index loads + 4 gathers in flight per sub-wave.
template <int D, bool BIAS_RELU>
__global__ __launch_bounds__(256) void k_agg3(const float* __restrict__ h,
                                              const int2* __restrict__ csr,
                                              const int* __restrict__ rowptr,
                                              const float* __restrict__ dinv,
                                              const float* __restrict__ bias,
                                              float* __restrict__ out) {
    constexpr int SUB = D / 4;        // lanes per node (16 for D=64, 32 for D=128)
    constexpr int NPB = 256 / SUB;    // nodes per block
    const int sub = threadIdx.x / SUB;
    const int sl = threadIdx.x % SUB;
    const int node = blockIdx.x * NPB + sub;
    if (node >= NN) return;

    const float dn = dinv[node];
    float4 acc;
    {
        float4 hv = *reinterpret_cast<const float4*>(h + (size_t)node * D + sl * 4);
        float w = dn * dn;
        acc.x = w * hv.x; acc.y = w * hv.y; acc.z = w * hv.z; acc.w = w * hv.w;
    }
    int j = rowptr[node];
    const int end = rowptr[node + 1];
    // peel one edge to align j to even (csr base is 16B-aligned)
    if ((j & 1) && j < end) {
        int2 e0 = csr[j];
        float w0 = __int_as_float(e0.y);
        float4 g0 = *reinterpret_cast<const float4*>(h + (size_t)e0.x * D + sl * 4);
        acc.x = fmaf(w0, g0.x, acc.x); acc.y = fmaf(w0, g0.y, acc.y);
        acc.z = fmaf(w0, g0.z, acc.z); acc.w = fmaf(w0, g0.w, acc.w);
        ++j;
    }
    // main: 4 edges per iteration, two int4 index loads, 4 independent gathers
    for (; j + 4 <= end; j += 4) {
        int4 p0 = *reinterpret_cast<const int4*>(&csr[j]);
        int4 p1 = *reinterpret_cast<const int4*>(&csr[j + 2]);
        float4 g0 = *reinterpret_cast<const float4*>(h + (size_t)p0.x * D + sl * 4);
        float4 g1 = *reinterpret_cast<const float4*>(h + (size_t)p0.z * D + sl * 4);
        float4 g2 = *reinterpret_cast<const float4*>(h + (size_t)p1.x * D + sl * 4);
        float4 g3 = *reinterpret_cast<const float4*>(h + (size_t)p1.z * D + sl * 4);
        float w0 = __int_as_float(p0.y), w1 = __int_as_float(p0.w);
        float w2 = __int_as_float(p1.y), w3 = __int_as_float(p1.w);
        acc.x = fmaf(w0, g0.x, acc.x); acc.y = fmaf(w0, g0.y, acc.y);
        acc.z = fmaf(w0, g0.z, acc.z); acc.w = fmaf(w0, g0.w, acc.w);
        acc.x = fmaf(w1, g1.x, acc.x); acc.y = fmaf(w1, g1.y, acc.y);
        acc.z = fmaf(w1, g1.z, acc.z); acc.w = fmaf(w1, g1.w, acc.w);
        acc.x = fmaf(w2, g2.x, acc.x); acc.y = fmaf(w2, g2.y, acc.y);
        acc.z = fmaf(w2, g2.z, acc.z); acc.w = fmaf(w2, g2.w, acc.w);
        acc.x = fmaf(w3, g3.x, acc.x); acc.y = fmaf(w3, g3.y, acc.y);
        acc.z = fmaf(w3, g3.z, acc.z); acc.w = fmaf(w3, g3.w, acc.w);
    }
    if (j + 2 <= end) {
        int4 p0 = *reinterpret_cast<const int4*>(&csr[j]);
        float4 g0 = *reinterpret_cast<const float4*>(h + (size_t)p0.x * D + sl * 4);
        float4 g1 = *reinterpret_cast<const float4*>(h + (size_t)p0.z * D + sl * 4);
        float w0 = __int_as_float(p0.y), w1 = __int_as_float(p0.w);
        acc.x = fmaf(w0, g0.x, acc.x); acc.y = fmaf(w0, g0.y, acc.y);
        acc.z = fmaf(w0, g0.z, acc.z); acc.w = fmaf(w0, g0.w, acc.w);
        acc.x = fmaf(w1, g1.x, acc.x); acc.y = fmaf(w1, g1.y, acc.y);
        acc.z = fmaf(w1, g1.z, acc.z); acc.w = fmaf(w1, g1.w, acc.w);
        j += 2;
    }
    if (j < end) {
        int2 e0 = csr[j];
        float w0 = __int_as_float(e0.y);
        float4 g0 = *reinterpret_cast<const float4*>(h + (size_t)e0.x * D + sl * 4);
        acc.x = fmaf(w0, g0.x, acc.x); acc.y = fmaf(w0, g0.y, acc.y);
        acc.z = fmaf(w0, g0.z, acc.z); acc.w = fmaf(w0, g0.w, acc.w);
    }
    if (BIAS_RELU) {
        float4 bb = *reinterpret_cast<const float4*>(bias + sl * 4);
        acc.x = fmaxf(acc.x + bb.x, 0.0f);
        acc.y = fmaxf(acc.y + bb.y, 0.0f);
        acc.z = fmaxf(acc.z + bb.z, 0.0f);
        acc.w = fmaxf(acc.w + bb.w, 0.0f);
    }
    *reinterpret_cast<float4*>(out + (size_t)node * D + sl * 4) = acc;
}

// ---------------- GEMM v3 (unchanged from round 5 — out of top-5 now) ----------------
__device__ inline float4 fmaf4(float s, float4 w, float4 a) {
    a.x = fmaf(s, w.x, a.x); a.y = fmaf(s, w.y, a.y);
    a.z = fmaf(s, w.z, a.z); a.w = fmaf(s, w.w, a.w);
    return a;
}

template <int DIN, bool BIAS_RELU>
__global__ __launch_bounds__(256) void k_gemm3(const float* __restrict__ A,
                                               const float* __restrict__ W,
                                               const float* __restrict__ bias,
                                               float* __restrict__ C) {
    constexpr int KT = 32;
    constexpr int NT = DIN / KT;  // k-tiles (2 or 4)
    constexpr int AP = KT + 4;    // padded sA row stride (36)
    __shared__ float sW[KT * DH];   // [k][c] row-major, 16 KB
    __shared__ float sA[64 * AP];   // [r][k] padded, 9.2 KB
    const int t = threadIdx.x;
    const int cg = t & 31;   // col group: cols cg*4..+3
    const int rg = t >> 5;   // row group: rows rg*8..+7
    const int row0 = blockIdx.x * 64;
    const int sr = t >> 2;   // staging row 0..63
    const int kq = t & 3;    // staging k-quad

    float4 acc[8];
#pragma unroll
    for (int j = 0; j < 8; ++j) acc[j] = make_float4(0.f, 0.f, 0.f, 0.f);

    for (int tile = 0; tile < NT; ++tile) {
        if (tile) __syncthreads();
        {
            const float4* Wg = reinterpret_cast<const float4*>(W + tile * KT * DH);
            float4* sW4 = reinterpret_cast<float4*>(sW);
#pragma unroll
            for (int i = 0; i < (KT * DH / 4) / 256; ++i)  // 4 iters
                sW4[t + 256 * i] = Wg[t + 256 * i];
        }
        {
            int gr = row0 + sr;
            float4 v0 = make_float4(0.f, 0.f, 0.f, 0.f), v1 = v0;
            if (gr < NN) {
                const float* Ag = A + (size_t)gr * DIN + tile * KT + kq * 8;
                v0 = *reinterpret_cast<const float4*>(Ag);
                v1 = *reinterpret_cast<const float4*>(Ag + 4);
            }
            *reinterpret_cast<float4*>(&sA[sr * AP + kq * 8]) = v0;
            *reinterpret_cast<float4*>(&sA[sr * AP + kq * 8 + 4]) = v1;
        }
        __syncthreads();
#pragma unroll 2
        for (int kk = 0; kk < KT; kk += 4) {
            float4 w0 = *reinterpret_cast<const float4*>(&sW[(kk + 0) * DH + cg * 4]);
            float4 w1 = *reinterpret_cast<const float4*>(&sW[(kk + 1) * DH + cg * 4]);
            float4 w2 = *reinterpret_cast<const float4*>(&sW[(kk + 2) * DH + cg * 4]);
            float4 w3 = *reinterpret_cast<const float4*>(&sW[(kk + 3) * DH + cg * 4]);
#pragma unroll
            for (int j = 0; j < 8; ++j) {
                float4 a = *reinterpret_cast<const float4*>(&sA[(rg * 8 + j) * AP + kk]);
                acc[j] = fmaf4(a.x, w0, acc[j]);
                acc[j] = fmaf4(a.y, w1, acc[j]);
                acc[j] = fmaf4(a.z, w2, acc[j]);
                acc[j] = fmaf4(a.w, w3, acc[j]);
            }
        }
    }
    float4 bb = make_float4(0.f, 0.f, 0.f, 0.f);
    if (BIAS_RELU) bb = *reinterpret_cast<const float4*>(bias + cg * 4);
#pragma unroll
    for (int j = 0; j < 8; ++j) {
        int gr = row0 + rg * 8 + j;
        if (gr < NN) {
            float4 r = acc[j];
            if (BIAS_RELU) {
                r.x = fmaxf(r.x + bb.x, 0.f); r.y = fmaxf(r.y + bb.y, 0.f);
                r.z = fmaxf(r.z + bb.z, 0.f); r.w = fmaxf(r.w + bb.w, 0.f);
            }
            *reinterpret_cast<float4*>(C + (size_t)gr * DH + cg * 4) = r;
        }
    }
}

// ---------------- pooling ----------------
__global__ void k_gstart_zero(const int* __restrict__ batch, int* __restrict__ gstart,
                              float* __restrict__ pooled) {
    int i = blockIdx.x * blockDim.x + threadIdx.x;
    if (i < NG * DH) pooled[i] = 0.0f;
    if (blockIdx.x == 0 && threadIdx.x <= NG) {
        int g = threadIdx.x;
        int lo = 0, hi = NN;
        while (lo < hi) {
            int mid = (lo + hi) >> 1;
            if (batch[mid] < g) lo = mid + 1; else hi = mid;
        }
        gstart[g] = lo;
    }
}

constexpr int POOL_CHUNK = 64;
__global__ __launch_bounds__(256) void k_pool2(const float* __restrict__ h,
                                               const int* __restrict__ batch,
                                               float* __restrict__ pooled) {
    const int c = threadIdx.x & 127;    // channel
    const int half = threadIdx.x >> 7;  // 0/1: interleaved nodes
    const int n0 = blockIdx.x * POOL_CHUNK;
    const int nEnd = min(n0 + POOL_CHUNK, NN);
    float acc = 0.0f;
    int gcur = -1;
    for (int n = n0 + half; n < nEnd; n += 2) {
        int g = batch[n];
        if (g != gcur) {
            if (gcur >= 0) atomicAdd(&pooled[gcur * DH + c], acc);
            acc = 0.0f;
            gcur = g;
        }
        acc += h[(size_t)n * DH + c];
    }
    if (gcur >= 0) atomicAdd(&pooled[gcur * DH + c], acc);
}

__global__ void k_head(const float* __restrict__ pooled, const int* __restrict__ gstart,
                       const float* __restrict__ Wf, const float* __restrict__ bf,
                       float* __restrict__ out) {
    int t = threadIdx.x;
    if (t >= NG * DO) return;
    int g = t / DO, o = t - g * DO;
    float acc = 0.0f;
    for (int k = 0; k < DH; ++k) acc += pooled[g * DH + k] * Wf[k * DO + o];
    float cnt = fmaxf((float)(gstart[g + 1] - gstart[g]), 1.0f);
    out[t] = acc / cnt + bf[o];
}

extern "C" void kernel_launch(void* const* d_in, const int* in_sizes, int n_in,
                              void* d_out, int out_size, void* d_ws, size_t ws_size,
                              hipStream_t stream) {
    const float* x   = (const float*)d_in[0];
    const int* ei    = (const int*)d_in[1];  // [2, NE] row-major
    const int* batch = (const int*)d_in[2];
    const float* W1  = (const float*)d_in[3];
    const float* b1  = (const float*)d_in[4];
    const float* W2  = (const float*)d_in[5];
    const float* b2  = (const float*)d_in[6];
    const float* Wf  = (const float*)d_in[7];
    const float* bf  = (const float*)d_in[8];
    float* out = (float*)d_out;

    const int* src = ei;
    const int* dst = ei + NE;

    // workspace layout (~58.3 MB); csr offset = 100432 ints = 401728 B (16B-aligned)
    int* cnt      = (int*)d_ws;              // 50048 (reused as cursor after scan3)
    int* rowptr   = cnt + 50048;             // 50056 (NN+1 used)
    int* partial  = rowptr + 50056;          // 256
    int* gstart   = partial + 256;           // 72
    int2* csr     = (int2*)(gstart + 72);    // 800000 int2
    float* dinv   = (float*)(csr + 800000);  // 50048
    float* buf1   = dinv + 50048;            // 6,400,000
    float* buf2   = buf1 + 6400000;          // 6,400,000
    float* pooled = buf2 + 6400000;          // 8192

    const int B = 256;
    k_zero_cnt<<<(NN + B - 1) / B, B, 0, stream>>>(cnt);
    k_hist<<<(NE + B - 1) / B, B, 0, stream>>>(dst, cnt);
    k_scan1<<<NB_SCAN, SCAN_B, 0, stream>>>(cnt, rowptr, partial);
    k_scan2<<<1, SCAN_B, 0, stream>>>(partial);
    k_scan3<<<(NN + B) / B, B, 0, stream>>>(rowptr, partial, cnt /*cursor*/, dinv);
    k_fill<<<(NE + B - 1) / B, B, 0, stream>>>(src, dst, cnt /*cursor*/, dinv, csr);

    const int gemmGrid = (NN + 63) / 64;  // 782

    // layer 1: agg first (D=64, linearity), then GEMM + bias + relu
    k_agg3<DI, false><<<NN / 16, 256, 0, stream>>>(x, csr, rowptr, dinv, nullptr, buf1);
    k_gemm3<DI, true><<<gemmGrid, 256, 0, stream>>>(buf1, W1, b1, buf2);  // h1

    // layer 2: GEMM first, then agg + bias + relu
    k_gemm3<DH, false><<<gemmGrid, 256, 0, stream>>>(buf2, W2, nullptr, buf1);  // t = h1@W2
    k_agg3<DH, true><<<NN / 8, 256, 0, stream>>>(buf1, csr, rowptr, dinv, b2, buf2);  // h2

    // pool + head
    k_gstart_zero<<<32, 256, 0, stream>>>(batch, gstart, pooled);
    k_pool2<<<(NN + POOL_CHUNK - 1) / POOL_CHUNK, 256, 0, stream>>>(buf2, batch, pooled);
    k_head<<<1, 256, 0, stream>>>(pooled, gstart, Wf, bf, out);
}